// Round 1
// baseline (488.557 us; speedup 1.0000x reference)
//
#include <hip/hip_runtime.h>
#include <hip/hip_bf16.h>

typedef __bf16 bf8 __attribute__((ext_vector_type(8)));
typedef float  f4  __attribute__((ext_vector_type(4)));

__device__ __forceinline__ unsigned f2bf(float f) {
  union { float f; unsigned u; } v; v.f = f;
  return (v.u + 0x7FFFu + ((v.u >> 16) & 1u)) >> 16;  // RNE f32->bf16
}

#define BM 128
#define BN 128
#define BK 64

__launch_bounds__(256, 2)
__global__ void woq_gemm(const float* __restrict__ x,
                         const int*   __restrict__ qweight,
                         const int*   __restrict__ qzeros,
                         const float* __restrict__ scales,
                         const float* __restrict__ bias,
                         float*       __restrict__ out,
                         int M, int N, int K) {
  // K-contiguous tiles, XOR-swizzled (byte ^= (row&7)<<4) to kill ds_read_b128
  // bank conflicts on 128B rows.
  __shared__ unsigned short sA[BM * BK];  // x tile   [m][k] bf16
  __shared__ unsigned short sB[BN * BK];  // W tile   [n][k] bf16

  const int t    = threadIdx.x;
  const int n0   = blockIdx.x * BN;
  const int m0   = blockIdx.y * BM;

  const int wid  = t >> 6, lane = t & 63;
  const int wr   = wid >> 1, wc = wid & 1;     // 2x2 waves of 64x64
  const int lr   = lane & 15, lk = lane >> 4;  // MFMA lane coords

  f4 acc[4][4] = {};

  // B-staging: this thread owns one output column c of the tile, two packed
  // rows per pass.
  const int c     = t & 127;
  const int rbase = t >> 7;  // 0 or 1

  const int segA  = t & 7;   // A-staging: 8-float segment
  const int rowbA = t >> 3;  // 0..31

  const int nK = K / BK;
  for (int kt = 0; kt < nK; ++kt) {
    const int k0 = kt * BK;
    __syncthreads();

    // ---- stage A: x[m0..+128][k0..+64] f32 -> bf16 LDS ----
    #pragma unroll
    for (int p = 0; p < 4; ++p) {
      int row = rowbA + p * 32;
      const float4* src = (const float4*)(x + (size_t)(m0 + row) * K + k0 + segA * 8);
      float4 f0 = src[0], f1 = src[1];
      uint4 w;
      w.x = f2bf(f0.x) | (f2bf(f0.y) << 16);
      w.y = f2bf(f0.z) | (f2bf(f0.w) << 16);
      w.z = f2bf(f1.x) | (f2bf(f1.y) << 16);
      w.w = f2bf(f1.z) | (f2bf(f1.w) << 16);
      unsigned off = (unsigned)(row * (BK * 2) + segA * 16) ^ ((row & 7) << 4);
      *(uint4*)((char*)sA + off) = w;
    }

    // ---- stage B: dequant qweight[k0/8..+8][n0..+128] -> bf16 [n][k] LDS ----
    {
      const int g = k0 >> 7;  // group (constant within aligned 64-row tile)
      const unsigned zq = (unsigned)qzeros[g * (N >> 3) + ((n0 + c) >> 3)];
      const int   zp = (int)((zq >> (4 * ((n0 + c) & 7))) & 0xFu) + 1;
      const float sc = scales[(size_t)g * N + n0 + c];
      #pragma unroll
      for (int p = 0; p < 4; ++p) {
        int r = rbase + p * 2;  // packed row 0..7
        unsigned uq = (unsigned)qweight[(size_t)(kt * 8 + r) * N + n0 + c];
        uint4 w;
        #pragma unroll
        for (int h = 0; h < 4; ++h) {
          int v0 = (int)((uq >> (8 * h))     & 0xFu) - zp;
          int v1 = (int)((uq >> (8 * h + 4)) & 0xFu) - zp;
          ((unsigned*)&w)[h] = f2bf((float)v0 * sc) | (f2bf((float)v1 * sc) << 16);
        }
        unsigned off = (unsigned)(c * (BK * 2) + r * 16) ^ ((c & 7) << 4);
        *(uint4*)((char*)sB + off) = w;
      }
    }
    __syncthreads();

    // ---- compute: 2 k-steps x 4x4 fragments of 16x16x32 ----
    #pragma unroll
    for (int ks = 0; ks < 2; ++ks) {
      bf8 a[4], b[4];
      #pragma unroll
      for (int mi = 0; mi < 4; ++mi) {
        int row = wr * 64 + mi * 16 + lr;
        unsigned off = (unsigned)(row * (BK * 2) + ks * 64 + lk * 16) ^ ((row & 7) << 4);
        a[mi] = *(const bf8*)((const char*)sA + off);
      }
      #pragma unroll
      for (int ni = 0; ni < 4; ++ni) {
        int rowN = wc * 64 + ni * 16 + lr;
        unsigned off = (unsigned)(rowN * (BK * 2) + ks * 64 + lk * 16) ^ ((rowN & 7) << 4);
        b[ni] = *(const bf8*)((const char*)sB + off);
      }
      #pragma unroll
      for (int mi = 0; mi < 4; ++mi)
        #pragma unroll
        for (int ni = 0; ni < 4; ++ni)
          acc[mi][ni] = __builtin_amdgcn_mfma_f32_16x16x32_bf16(a[mi], b[ni], acc[mi][ni], 0, 0, 0);
    }
  }

  // ---- epilogue: C/D layout col=lane&15, row=(lane>>4)*4+reg ----
  #pragma unroll
  for (int ni = 0; ni < 4; ++ni) {
    int col = n0 + wc * 64 + ni * 16 + lr;
    float bv = bias[col];
    #pragma unroll
    for (int mi = 0; mi < 4; ++mi) {
      int row = m0 + wr * 64 + mi * 16 + lk * 4;
      #pragma unroll
      for (int r = 0; r < 4; ++r)
        out[(size_t)(row + r) * N + col] = acc[mi][ni][r] + bv;
    }
  }
}

extern "C" void kernel_launch(void* const* d_in, const int* in_sizes, int n_in,
                              void* d_out, int out_size, void* d_ws, size_t ws_size,
                              hipStream_t stream) {
  const float* x  = (const float*)d_in[0];
  const int*   qw = (const int*)d_in[1];
  const int*   qz = (const int*)d_in[2];
  const float* sc = (const float*)d_in[3];
  const float* bs = (const float*)d_in[4];
  float* out = (float*)d_out;

  const int out_f  = in_sizes[4];                                // 4096
  const int in_f   = (int)(((long long)in_sizes[1] * 8) / out_f); // 4096
  const int tokens = (int)((long long)in_sizes[0] / in_f);        // 8192

  dim3 grid(out_f / BN, tokens / BM);
  woq_gemm<<<grid, 256, 0, stream>>>(x, qw, qz, sc, bs, out, tokens, out_f, in_f);
}

// Round 2
// 380.605 us; speedup vs baseline: 1.2836x; 1.2836x over previous
//
#include <hip/hip_runtime.h>
#include <hip/hip_bf16.h>
#include <stdint.h>

typedef __bf16 bf8 __attribute__((ext_vector_type(8)));
typedef float  f4  __attribute__((ext_vector_type(4)));

__device__ __forceinline__ unsigned f2bf(float f) {
  union { float f; unsigned u; } v; v.f = f;
  return (v.u + 0x7FFFu + ((v.u >> 16) & 1u)) >> 16;  // RNE f32->bf16
}

// async global->LDS, 16B per lane; dest = wave-uniform base + lane*16
__device__ __forceinline__ void gload_lds16(const void* g, void* l) {
  __builtin_amdgcn_global_load_lds(
      (const __attribute__((address_space(1))) void*)(uintptr_t)g,
      (__attribute__((address_space(3))) void*)(uint32_t)(uintptr_t)l,
      16, 0, 0);
}

// ---------------- pass 1a: x f32 -> bf16 ----------------
__global__ void cvt_x(const float4* __restrict__ x, uint4* __restrict__ xb, int n16) {
  int i = blockIdx.x * blockDim.x + threadIdx.x;
  if (i >= n16) return;
  float4 f0 = x[2 * i], f1 = x[2 * i + 1];
  uint4 w;
  w.x = f2bf(f0.x) | (f2bf(f0.y) << 16);
  w.y = f2bf(f0.z) | (f2bf(f0.w) << 16);
  w.z = f2bf(f1.x) | (f2bf(f1.y) << 16);
  w.w = f2bf(f1.z) | (f2bf(f1.w) << 16);
  xb[i] = w;
}

// ---------------- pass 1b: dequant qweight -> W^T bf16 [N][K] ----------------
__global__ void dq_w(const int* __restrict__ qw, const int* __restrict__ qz,
                     const float* __restrict__ sc, unsigned short* __restrict__ wt,
                     int N, int K, int group_size) {
  int id = blockIdx.x * blockDim.x + threadIdx.x;  // N*K/64 threads
  int n  = id % N;
  int kb = id / N;                  // 64-k block
  if (kb >= K / 64) return;
  int g = (kb * 64) / group_size;
  unsigned zq = ((unsigned)qz[g * (N >> 3) + (n >> 3)] >> (4 * (n & 7))) & 0xFu;
  float zs = (float)(int)(zq + 1u);
  float s  = sc[(size_t)g * N + n];
  #pragma unroll
  for (int r = 0; r < 8; ++r) {
    unsigned q = (unsigned)qw[(size_t)(kb * 8 + r) * N + n];
    uint4 w;
    #pragma unroll
    for (int h = 0; h < 4; ++h) {
      float v0 = (float)(int)((q >> (8 * h))     & 0xFu) - zs;
      float v1 = (float)(int)((q >> (8 * h + 4)) & 0xFu) - zs;
      ((unsigned*)&w)[h] = f2bf(v0 * s) | (f2bf(v1 * s) << 16);
    }
    *(uint4*)(wt + (size_t)n * K + kb * 64 + r * 8) = w;
  }
}

// ---------------- pass 2: bf16 GEMM (m97 structure) ----------------
#define BM 128
#define BN 128
#define BK 64

__launch_bounds__(256, 2)
__global__ void gemm_bf16(const unsigned short* __restrict__ A,  // [M][K] bf16
                          const unsigned short* __restrict__ B,  // [N][K] bf16
                          const float* __restrict__ bias,
                          float* __restrict__ out,
                          int M, int N, int K) {
  __shared__ __align__(16) unsigned short sA[BM * BK];
  __shared__ __align__(16) unsigned short sB[BN * BK];

  // XCD-bijective swizzle (nwg % 8 == 0)
  const int nbx = gridDim.x;
  const int nwg = gridDim.x * gridDim.y;
  const int id  = blockIdx.y * nbx + blockIdx.x;
  const int cpx = nwg >> 3;
  const int swz = (id & 7) * cpx + (id >> 3);
  const int m0 = (swz / nbx) * BM;
  const int n0 = (swz % nbx) * BN;

  const int t = threadIdx.x;
  const int wid = t >> 6, lane = t & 63;
  const int wr = wid >> 1, wc = wid & 1;       // 2x2 waves of 64x64
  const int lr = lane & 15, lk = lane >> 4;

  const int srow = lane >> 3;        // staging: row within 8-row segment
  const int scol = (lane & 7) * 8;   // staging: k element offset

  f4 acc[4][4] = {};

  const int nK = K / BK;
  for (int kt = 0; kt < nK; ++kt) {
    const int k0 = kt * BK;
    __syncthreads();
    #pragma unroll
    for (int i = 0; i < 4; ++i) {
      const int seg = wid * 4 + i;         // 16 segments x 8 rows
      const int row = seg * 8 + srow;
      gload_lds16(A + (size_t)(m0 + row) * K + k0 + scol, sA + seg * 512);
      gload_lds16(B + (size_t)(n0 + row) * K + k0 + scol, sB + seg * 512);
    }
    __syncthreads();  // compiler drains vmcnt(0) here

    #pragma unroll
    for (int ks = 0; ks < 2; ++ks) {
      bf8 a[4], b[4];
      #pragma unroll
      for (int mi = 0; mi < 4; ++mi)
        a[mi] = *(const bf8*)(sA + (wr * 64 + mi * 16 + lr) * BK + ks * 32 + lk * 8);
      #pragma unroll
      for (int ni = 0; ni < 4; ++ni)
        b[ni] = *(const bf8*)(sB + (wc * 64 + ni * 16 + lr) * BK + ks * 32 + lk * 8);
      #pragma unroll
      for (int mi = 0; mi < 4; ++mi)
        #pragma unroll
        for (int ni = 0; ni < 4; ++ni)
          acc[mi][ni] = __builtin_amdgcn_mfma_f32_16x16x32_bf16(a[mi], b[ni], acc[mi][ni], 0, 0, 0);
    }
  }

  // epilogue: C/D layout col=lane&15, row=(lane>>4)*4+reg
  #pragma unroll
  for (int ni = 0; ni < 4; ++ni) {
    int col = n0 + wc * 64 + ni * 16 + lr;
    float bv = bias[col];
    #pragma unroll
    for (int mi = 0; mi < 4; ++mi) {
      int row = m0 + wr * 64 + mi * 16 + lk * 4;
      #pragma unroll
      for (int r = 0; r < 4; ++r)
        out[(size_t)(row + r) * N + col] = acc[mi][ni][r] + bv;
    }
  }
}

// ---------------- fallback: round-1 fused kernel (if ws too small) ----------------
__launch_bounds__(256, 2)
__global__ void woq_gemm(const float* __restrict__ x,
                         const int*   __restrict__ qweight,
                         const int*   __restrict__ qzeros,
                         const float* __restrict__ scales,
                         const float* __restrict__ bias,
                         float*       __restrict__ out,
                         int M, int N, int K) {
  __shared__ unsigned short sA[BM * BK];
  __shared__ unsigned short sB[BN * BK];
  const int t = threadIdx.x;
  const int n0 = blockIdx.x * BN, m0 = blockIdx.y * BM;
  const int wid = t >> 6, lane = t & 63;
  const int wr = wid >> 1, wc = wid & 1;
  const int lr = lane & 15, lk = lane >> 4;
  f4 acc[4][4] = {};
  const int c = t & 127, rbase = t >> 7;
  const int segA = t & 7, rowbA = t >> 3;
  const int nK = K / BK;
  for (int kt = 0; kt < nK; ++kt) {
    const int k0 = kt * BK;
    __syncthreads();
    #pragma unroll
    for (int p = 0; p < 4; ++p) {
      int row = rowbA + p * 32;
      const float4* src = (const float4*)(x + (size_t)(m0 + row) * K + k0 + segA * 8);
      float4 f0 = src[0], f1 = src[1];
      uint4 w;
      w.x = f2bf(f0.x) | (f2bf(f0.y) << 16);
      w.y = f2bf(f0.z) | (f2bf(f0.w) << 16);
      w.z = f2bf(f1.x) | (f2bf(f1.y) << 16);
      w.w = f2bf(f1.z) | (f2bf(f1.w) << 16);
      unsigned off = (unsigned)(row * (BK * 2) + segA * 16) ^ ((row & 7) << 4);
      *(uint4*)((char*)sA + off) = w;
    }
    {
      const int g = k0 >> 7;
      const unsigned zq = (unsigned)qzeros[g * (N >> 3) + ((n0 + c) >> 3)];
      const int   zp = (int)((zq >> (4 * ((n0 + c) & 7))) & 0xFu) + 1;
      const float sc = scales[(size_t)g * N + n0 + c];
      #pragma unroll
      for (int p = 0; p < 4; ++p) {
        int r = rbase + p * 2;
        unsigned uq = (unsigned)qweight[(size_t)(kt * 8 + r) * N + n0 + c];
        uint4 w;
        #pragma unroll
        for (int h = 0; h < 4; ++h) {
          int v0 = (int)((uq >> (8 * h))     & 0xFu) - zp;
          int v1 = (int)((uq >> (8 * h + 4)) & 0xFu) - zp;
          ((unsigned*)&w)[h] = f2bf((float)v0 * sc) | (f2bf((float)v1 * sc) << 16);
        }
        unsigned off = (unsigned)(c * (BK * 2) + r * 16) ^ ((c & 7) << 4);
        *(uint4*)((char*)sB + off) = w;
      }
    }
    __syncthreads();
    #pragma unroll
    for (int ks = 0; ks < 2; ++ks) {
      bf8 a[4], b[4];
      #pragma unroll
      for (int mi = 0; mi < 4; ++mi) {
        int row = wr * 64 + mi * 16 + lr;
        unsigned off = (unsigned)(row * (BK * 2) + ks * 64 + lk * 16) ^ ((row & 7) << 4);
        a[mi] = *(const bf8*)((const char*)sA + off);
      }
      #pragma unroll
      for (int ni = 0; ni < 4; ++ni) {
        int rowN = wc * 64 + ni * 16 + lr;
        unsigned off = (unsigned)(rowN * (BK * 2) + ks * 64 + lk * 16) ^ ((rowN & 7) << 4);
        b[ni] = *(const bf8*)((const char*)sB + off);
      }
      #pragma unroll
      for (int mi = 0; mi < 4; ++mi)
        #pragma unroll
        for (int ni = 0; ni < 4; ++ni)
          acc[mi][ni] = __builtin_amdgcn_mfma_f32_16x16x32_bf16(a[mi], b[ni], acc[mi][ni], 0, 0, 0);
    }
  }
  #pragma unroll
  for (int ni = 0; ni < 4; ++ni) {
    int col = n0 + wc * 64 + ni * 16 + lr;
    float bv = bias[col];
    #pragma unroll
    for (int mi = 0; mi < 4; ++mi) {
      int row = m0 + wr * 64 + mi * 16 + lk * 4;
      #pragma unroll
      for (int r = 0; r < 4; ++r)
        out[(size_t)(row + r) * N + col] = acc[mi][ni][r] + bv;
    }
  }
}

extern "C" void kernel_launch(void* const* d_in, const int* in_sizes, int n_in,
                              void* d_out, int out_size, void* d_ws, size_t ws_size,
                              hipStream_t stream) {
  const float* x  = (const float*)d_in[0];
  const int*   qw = (const int*)d_in[1];
  const int*   qz = (const int*)d_in[2];
  const float* sc = (const float*)d_in[3];
  const float* bs = (const float*)d_in[4];
  float* out = (float*)d_out;

  const int N = in_sizes[4];                                   // out_f = 4096
  const int K = (int)(((long long)in_sizes[1] * 8) / N);       // in_f  = 4096
  const int M = (int)((long long)in_sizes[0] / K);             // tokens = 8192
  const int n_groups   = (int)((long long)in_sizes[3] / N);
  const int group_size = K / n_groups;

  const size_t need = ((size_t)M * K + (size_t)N * K) * 2;
  if (ws_size >= need) {
    unsigned short* xb = (unsigned short*)d_ws;          // [M][K] bf16
    unsigned short* wt = xb + (size_t)M * K;             // [N][K] bf16

    int n16 = M * K / 8;
    cvt_x<<<(n16 + 255) / 256, 256, 0, stream>>>((const float4*)x, (uint4*)xb, n16);

    int ndq = N * (K / 64);
    dq_w<<<(ndq + 255) / 256, 256, 0, stream>>>(qw, qz, sc, wt, N, K, group_size);

    dim3 grid(N / BN, M / BM);
    gemm_bf16<<<grid, 256, 0, stream>>>(xb, wt, bs, out, M, N, K);
  } else {
    dim3 grid(N / BN, M / BM);
    woq_gemm<<<grid, 256, 0, stream>>>(x, qw, qz, sc, bs, out, M, N, K);
  }
}

// Round 3
// 323.058 us; speedup vs baseline: 1.5123x; 1.1781x over previous
//
#include <hip/hip_runtime.h>
#include <hip/hip_bf16.h>
#include <stdint.h>

typedef __bf16 bf8 __attribute__((ext_vector_type(8)));
typedef float  f4  __attribute__((ext_vector_type(4)));

__device__ __forceinline__ unsigned f2bf(float f) {
  union { float f; unsigned u; } v; v.f = f;
  return (v.u + 0x7FFFu + ((v.u >> 16) & 1u)) >> 16;  // RNE f32->bf16
}

// async global->LDS, 16B/lane; LDS dest = wave-uniform base + lane*16
__device__ __forceinline__ void gload_lds16(const void* g, void* l) {
  __builtin_amdgcn_global_load_lds(
      (const __attribute__((address_space(1))) void*)(uintptr_t)g,
      (__attribute__((address_space(3))) void*)(uint32_t)(uintptr_t)l,
      16, 0, 0);
}

// ---------------- pass 1a: x f32 -> bf16 ----------------
__global__ void cvt_x(const float4* __restrict__ x, uint4* __restrict__ xb, int n16) {
  int i = blockIdx.x * blockDim.x + threadIdx.x;
  if (i >= n16) return;
  float4 f0 = x[2 * i], f1 = x[2 * i + 1];
  uint4 w;
  w.x = f2bf(f0.x) | (f2bf(f0.y) << 16);
  w.y = f2bf(f0.z) | (f2bf(f0.w) << 16);
  w.z = f2bf(f1.x) | (f2bf(f1.y) << 16);
  w.w = f2bf(f1.z) | (f2bf(f1.w) << 16);
  xb[i] = w;
}

// ---------------- pass 1b: dequant qweight -> W^T bf16 [N][K] ----------------
__global__ void dq_w(const int* __restrict__ qw, const int* __restrict__ qz,
                     const float* __restrict__ sc, unsigned short* __restrict__ wt,
                     int N, int K, int group_size) {
  int id = blockIdx.x * blockDim.x + threadIdx.x;  // N*K/64 threads
  int n  = id % N;
  int kb = id / N;                  // 64-k block
  if (kb >= K / 64) return;
  int g = (kb * 64) / group_size;
  unsigned zq = ((unsigned)qz[g * (N >> 3) + (n >> 3)] >> (4 * (n & 7))) & 0xFu;
  float zs = (float)(int)(zq + 1u);
  float s  = sc[(size_t)g * N + n];
  #pragma unroll
  for (int r = 0; r < 8; ++r) {
    unsigned q = (unsigned)qw[(size_t)(kb * 8 + r) * N + n];
    uint4 w;
    #pragma unroll
    for (int h = 0; h < 4; ++h) {
      float v0 = (float)(int)((q >> (8 * h))     & 0xFu) - zs;
      float v1 = (float)(int)((q >> (8 * h + 4)) & 0xFu) - zs;
      ((unsigned*)&w)[h] = f2bf(v0 * s) | (f2bf(v1 * s) << 16);
    }
    *(uint4*)(wt + (size_t)n * K + kb * 64 + r * 8) = w;
  }
}

// ---------------- pass 2: 256^2 8-phase bf16 GEMM ----------------
// LDS per K-tile buffer: A 32KB + B 32KB, double-buffered = 128KB.
// Layout: subtile-contiguous [rowgrp(16)][colgrp(2)] x 1024B (16 rows x 32 cols
// bf16). Each gload_lds writes one full subtile (lane l -> row l>>2, col
// (l&3)*8); each frag ds_read_b128 reads one full subtile -> both sides are
// uniform over all 32 banks -> conflict-free without XOR swizzle.
#define BM 256
#define BN 256
#define BK 64

__launch_bounds__(512, 2)
__global__ void gemm_8ph(const unsigned short* __restrict__ A,  // [M][K] bf16
                         const unsigned short* __restrict__ B,  // [N][K] bf16
                         const float* __restrict__ bias,
                         float* __restrict__ out,
                         int M, int N, int K) {
  __shared__ __align__(16) char smem[131072];

  const int nbx = N / BN;
  const int nwg = (M / BM) * nbx;
  const int id  = blockIdx.y * gridDim.x + blockIdx.x;
  const int cpx = nwg >> 3;                       // nwg % 8 == 0 (512)
  const int swzid = (id & 7) * cpx + (id >> 3);   // XCD-contiguous chunks
  const int m0 = (swzid / nbx) * BM;
  const int n0 = (swzid % nbx) * BN;

  const int t    = threadIdx.x;
  const int wid  = t >> 6, lane = t & 63;
  const int wr   = wid >> 2, wc = wid & 3;        // 2(M) x 4(N) waves
  const int lr   = lane & 15, lk = lane >> 4;
  const unsigned loff = (unsigned)(lr * 64 + lk * 16);  // byte off in subtile

  const int srow = lane >> 2;        // staging: row within subtile
  const int scol = (lane & 3) * 8;   // staging: col element within 32-col grp

  f4 acc[8][4] = {};

  const int nK = K / BK;

  // Stage one half-tile (128 rows x 64 k): wave w stages row-group w, both
  // col-groups -> 2 gload_lds per wave per phase.
#define STAGE_A(tile, h)                                                          \
  {                                                                               \
    const int _tt = (tile);                                                       \
    _Pragma("unroll")                                                             \
    for (int cg = 0; cg < 2; ++cg) {                                              \
      const unsigned short* _src = A + (size_t)(m0 + (h) * 128 + wid * 16 + srow) * K \
                                     + _tt * BK + cg * 32 + scol;                 \
      char* _dst = smem + (_tt & 1) * 65536 + ((((h) * 8 + wid) * 2 + cg) << 10); \
      gload_lds16(_src, _dst);                                                    \
    }                                                                             \
  }
#define STAGE_B(tile, h)                                                          \
  {                                                                               \
    const int _tt = (tile);                                                       \
    _Pragma("unroll")                                                             \
    for (int cg = 0; cg < 2; ++cg) {                                              \
      const unsigned short* _src = B + (size_t)(n0 + (h) * 128 + wid * 16 + srow) * K \
                                     + _tt * BK + cg * 32 + scol;                 \
      char* _dst = smem + (_tt & 1) * 65536 + 32768 +                             \
                   ((((h) * 8 + wid) * 2 + cg) << 10);                            \
      gload_lds16(_src, _dst);                                                    \
    }                                                                             \
  }

  // Prologue: issue tile0 {B0,B1,A0,A1}, tile1 {B0,B1}; drain so tile0 is
  // complete (all but last 4 issues), barrier.
  STAGE_B(0, 0); STAGE_B(0, 1);
  STAGE_A(0, 0); STAGE_A(0, 1);
  if (nK > 1) {
    STAGE_B(1, 0); STAGE_B(1, 1);
    asm volatile("s_waitcnt vmcnt(4)" ::: "memory");
  } else {
    asm volatile("s_waitcnt vmcnt(0)" ::: "memory");
  }
  __builtin_amdgcn_s_barrier();
  __builtin_amdgcn_sched_barrier(0);

  bf8 a[4][2], b[4][2];

  for (int kt = 0; kt < nK; ++kt) {
    const char* pA = smem + (kt & 1) * 65536;
    const char* pB = pA + 32768;
    const int ra = wr * 8;   // A row-group base (mh=0)
    const int rb = wc * 4;   // B row-group base

    // ---- phase 0: Q(mh0, nf0-1); stage A0 of tile kt+1 ----
    if (kt + 1 < nK) STAGE_A(kt + 1, 0);
    #pragma unroll
    for (int mf = 0; mf < 4; ++mf)
      #pragma unroll
      for (int ks = 0; ks < 2; ++ks)
        a[mf][ks] = *(const bf8*)(pA + (unsigned)((((ra + mf) * 2 + ks) << 10)) + loff);
    #pragma unroll
    for (int nf = 0; nf < 2; ++nf)
      #pragma unroll
      for (int ks = 0; ks < 2; ++ks)
        b[nf][ks] = *(const bf8*)(pB + (unsigned)((((rb + nf) * 2 + ks) << 10)) + loff);
    __builtin_amdgcn_s_barrier();
    __builtin_amdgcn_s_setprio(1);
    #pragma unroll
    for (int mf = 0; mf < 4; ++mf)
      #pragma unroll
      for (int nf = 0; nf < 2; ++nf)
        #pragma unroll
        for (int ks = 0; ks < 2; ++ks)
          acc[mf][nf] = __builtin_amdgcn_mfma_f32_16x16x32_bf16(a[mf][ks], b[nf][ks], acc[mf][nf], 0, 0, 0);
    __builtin_amdgcn_s_setprio(0);
    __builtin_amdgcn_s_barrier();

    // ---- phase 1: Q(mh0, nf2-3); stage A1 of tile kt+1 ----
    if (kt + 1 < nK) STAGE_A(kt + 1, 1);
    #pragma unroll
    for (int nf = 2; nf < 4; ++nf)
      #pragma unroll
      for (int ks = 0; ks < 2; ++ks)
        b[nf][ks] = *(const bf8*)(pB + (unsigned)((((rb + nf) * 2 + ks) << 10)) + loff);
    __builtin_amdgcn_s_barrier();
    __builtin_amdgcn_s_setprio(1);
    #pragma unroll
    for (int mf = 0; mf < 4; ++mf)
      #pragma unroll
      for (int nf = 2; nf < 4; ++nf)
        #pragma unroll
        for (int ks = 0; ks < 2; ++ks)
          acc[mf][nf] = __builtin_amdgcn_mfma_f32_16x16x32_bf16(a[mf][ks], b[nf][ks], acc[mf][nf], 0, 0, 0);
    __builtin_amdgcn_s_setprio(0);
    __builtin_amdgcn_s_barrier();

    // ---- phase 2: Q(mh1, nf2-3); stage B0 of tile kt+2 (region freed @ph1) ----
    if (kt + 2 < nK) STAGE_B(kt + 2, 0);
    #pragma unroll
    for (int mf = 0; mf < 4; ++mf)
      #pragma unroll
      for (int ks = 0; ks < 2; ++ks)
        a[mf][ks] = *(const bf8*)(pA + (unsigned)((((ra + 4 + mf) * 2 + ks) << 10)) + loff);
    __builtin_amdgcn_s_barrier();
    __builtin_amdgcn_s_setprio(1);
    #pragma unroll
    for (int mf = 0; mf < 4; ++mf)
      #pragma unroll
      for (int nf = 2; nf < 4; ++nf)
        #pragma unroll
        for (int ks = 0; ks < 2; ++ks)
          acc[4 + mf][nf] = __builtin_amdgcn_mfma_f32_16x16x32_bf16(a[mf][ks], b[nf][ks], acc[4 + mf][nf], 0, 0, 0);
    __builtin_amdgcn_s_setprio(0);
    __builtin_amdgcn_s_barrier();

    // ---- phase 3: Q(mh1, nf0-1); stage B1 of tile kt+2; counted drain ----
    if (kt + 2 < nK) {
      STAGE_B(kt + 2, 1);
      asm volatile("s_waitcnt vmcnt(4)" ::: "memory");  // tile kt+1 complete
    } else {
      asm volatile("s_waitcnt vmcnt(0)" ::: "memory");  // tail: drain all
    }
    __builtin_amdgcn_s_barrier();
    __builtin_amdgcn_sched_barrier(0);
    __builtin_amdgcn_s_setprio(1);
    #pragma unroll
    for (int mf = 0; mf < 4; ++mf)
      #pragma unroll
      for (int nf = 0; nf < 2; ++nf)
        #pragma unroll
        for (int ks = 0; ks < 2; ++ks)
          acc[4 + mf][nf] = __builtin_amdgcn_mfma_f32_16x16x32_bf16(a[mf][ks], b[nf][ks], acc[4 + mf][nf], 0, 0, 0);
    __builtin_amdgcn_s_setprio(0);
    __builtin_amdgcn_s_barrier();
  }

  // ---- epilogue: C/D layout col=lane&15, row=(lane>>4)*4+reg ----
  #pragma unroll
  for (int ni = 0; ni < 4; ++ni) {
    int col = n0 + wc * 64 + ni * 16 + lr;
    float bv = bias[col];
    #pragma unroll
    for (int mi = 0; mi < 8; ++mi) {
      int row = m0 + wr * 128 + mi * 16 + lk * 4;
      #pragma unroll
      for (int r = 0; r < 4; ++r)
        out[(size_t)(row + r) * N + col] = acc[mi][ni][r] + bv;
    }
  }
#undef STAGE_A
#undef STAGE_B
}

// ---------------- fallback (ws too small): round-1 fused kernel ----------------
#define FBM 128
#define FBN 128
#define FBK 64
__launch_bounds__(256, 2)
__global__ void woq_gemm(const float* __restrict__ x,
                         const int*   __restrict__ qweight,
                         const int*   __restrict__ qzeros,
                         const float* __restrict__ scales,
                         const float* __restrict__ bias,
                         float*       __restrict__ out,
                         int M, int N, int K) {
  __shared__ unsigned short sA[FBM * FBK];
  __shared__ unsigned short sB[FBN * FBK];
  const int t = threadIdx.x;
  const int n0 = blockIdx.x * FBN, m0 = blockIdx.y * FBM;
  const int wid = t >> 6, lane = t & 63;
  const int wr = wid >> 1, wc = wid & 1;
  const int lr = lane & 15, lk = lane >> 4;
  f4 acc[4][4] = {};
  const int c = t & 127, rbase = t >> 7;
  const int segA = t & 7, rowbA = t >> 3;
  const int nK = K / FBK;
  for (int kt = 0; kt < nK; ++kt) {
    const int k0 = kt * FBK;
    __syncthreads();
    #pragma unroll
    for (int p = 0; p < 4; ++p) {
      int row = rowbA + p * 32;
      const float4* src = (const float4*)(x + (size_t)(m0 + row) * K + k0 + segA * 8);
      float4 f0 = src[0], f1 = src[1];
      uint4 w;
      w.x = f2bf(f0.x) | (f2bf(f0.y) << 16);
      w.y = f2bf(f0.z) | (f2bf(f0.w) << 16);
      w.z = f2bf(f1.x) | (f2bf(f1.y) << 16);
      w.w = f2bf(f1.z) | (f2bf(f1.w) << 16);
      unsigned off = (unsigned)(row * (FBK * 2) + segA * 16) ^ ((row & 7) << 4);
      *(uint4*)((char*)sA + off) = w;
    }
    {
      const int g = k0 >> 7;
      const unsigned zq = (unsigned)qzeros[g * (N >> 3) + ((n0 + c) >> 3)];
      const int   zp = (int)((zq >> (4 * ((n0 + c) & 7))) & 0xFu) + 1;
      const float sc = scales[(size_t)g * N + n0 + c];
      #pragma unroll
      for (int p = 0; p < 4; ++p) {
        int r = rbase + p * 2;
        unsigned uq = (unsigned)qweight[(size_t)(kt * 8 + r) * N + n0 + c];
        uint4 w;
        #pragma unroll
        for (int h = 0; h < 4; ++h) {
          int v0 = (int)((uq >> (8 * h))     & 0xFu) - zp;
          int v1 = (int)((uq >> (8 * h + 4)) & 0xFu) - zp;
          ((unsigned*)&w)[h] = f2bf((float)v0 * sc) | (f2bf((float)v1 * sc) << 16);
        }
        unsigned off = (unsigned)(c * (FBK * 2) + r * 16) ^ ((c & 7) << 4);
        *(uint4*)((char*)sB + off) = w;
      }
    }
    __syncthreads();
    #pragma unroll
    for (int ks = 0; ks < 2; ++ks) {
      bf8 a[4], b[4];
      #pragma unroll
      for (int mi = 0; mi < 4; ++mi) {
        int row = wr * 64 + mi * 16 + lr;
        unsigned off = (unsigned)(row * (FBK * 2) + ks * 64 + lk * 16) ^ ((row & 7) << 4);
        a[mi] = *(const bf8*)((const char*)sA + off);
      }
      #pragma unroll
      for (int ni = 0; ni < 4; ++ni) {
        int rowN = wc * 64 + ni * 16 + lr;
        unsigned off = (unsigned)(rowN * (FBK * 2) + ks * 64 + lk * 16) ^ ((rowN & 7) << 4);
        b[ni] = *(const bf8*)((const char*)sB + off);
      }
      #pragma unroll
      for (int mi = 0; mi < 4; ++mi)
        #pragma unroll
        for (int ni = 0; ni < 4; ++ni)
          acc[mi][ni] = __builtin_amdgcn_mfma_f32_16x16x32_bf16(a[mi], b[ni], acc[mi][ni], 0, 0, 0);
    }
  }
  #pragma unroll
  for (int ni = 0; ni < 4; ++ni) {
    int col = n0 + wc * 64 + ni * 16 + lr;
    float bv = bias[col];
    #pragma unroll
    for (int mi = 0; mi < 4; ++mi) {
      int row = m0 + wr * 64 + mi * 16 + lk * 4;
      #pragma unroll
      for (int r = 0; r < 4; ++r)
        out[(size_t)(row + r) * N + col] = acc[mi][ni][r] + bv;
    }
  }
}

extern "C" void kernel_launch(void* const* d_in, const int* in_sizes, int n_in,
                              void* d_out, int out_size, void* d_ws, size_t ws_size,
                              hipStream_t stream) {
  const float* x  = (const float*)d_in[0];
  const int*   qw = (const int*)d_in[1];
  const int*   qz = (const int*)d_in[2];
  const float* sc = (const float*)d_in[3];
  const float* bs = (const float*)d_in[4];
  float* out = (float*)d_out;

  const int N = in_sizes[4];
  const int K = (int)(((long long)in_sizes[1] * 8) / N);
  const int M = (int)((long long)in_sizes[0] / K);
  const int n_groups   = (int)((long long)in_sizes[3] / N);
  const int group_size = K / n_groups;

  const size_t need = ((size_t)M * K + (size_t)N * K) * 2;
  if (ws_size >= need && (M % BM) == 0 && (N % BN) == 0 && (K % BK) == 0 &&
      ((M / BM) * (N / BN)) % 8 == 0) {
    unsigned short* xb = (unsigned short*)d_ws;          // [M][K] bf16
    unsigned short* wt = xb + (size_t)M * K;             // [N][K] bf16

    int n16 = M * K / 8;
    cvt_x<<<(n16 + 255) / 256, 256, 0, stream>>>((const float4*)x, (uint4*)xb, n16);

    int ndq = N * (K / 64);
    dq_w<<<(ndq + 255) / 256, 256, 0, stream>>>(qw, qz, sc, wt, N, K, group_size);

    dim3 grid(N / BN, M / BM);
    gemm_8ph<<<grid, 512, 0, stream>>>(xb, wt, bs, out, M, N, K);
  } else {
    dim3 grid(N / FBN, M / FBM);
    woq_gemm<<<grid, 256, 0, stream>>>(x, qw, qz, sc, bs, out, M, N, K);
  }
}

// Round 4
// 301.650 us; speedup vs baseline: 1.6196x; 1.0710x over previous
//
#include <hip/hip_runtime.h>
#include <hip/hip_bf16.h>
#include <stdint.h>

typedef __bf16 bf8 __attribute__((ext_vector_type(8)));
typedef float  f4  __attribute__((ext_vector_type(4)));

__device__ __forceinline__ unsigned f2bf(float f) {
  union { float f; unsigned u; } v; v.f = f;
  return (v.u + 0x7FFFu + ((v.u >> 16) & 1u)) >> 16;  // RNE f32->bf16
}

// async global->LDS, 16B/lane; LDS dest = wave-uniform base + lane*16
__device__ __forceinline__ void gload_lds16(const void* g, void* l) {
  __builtin_amdgcn_global_load_lds(
      (const __attribute__((address_space(1))) void*)(uintptr_t)g,
      (__attribute__((address_space(3))) void*)(uint32_t)(uintptr_t)l,
      16, 0, 0);
}

// ---------------- pass 1a: x f32 -> bf16 ----------------
__global__ void cvt_x(const float4* __restrict__ x, uint4* __restrict__ xb, int n16) {
  int i = blockIdx.x * blockDim.x + threadIdx.x;
  if (i >= n16) return;
  float4 f0 = x[2 * i], f1 = x[2 * i + 1];
  uint4 w;
  w.x = f2bf(f0.x) | (f2bf(f0.y) << 16);
  w.y = f2bf(f0.z) | (f2bf(f0.w) << 16);
  w.z = f2bf(f1.x) | (f2bf(f1.y) << 16);
  w.w = f2bf(f1.z) | (f2bf(f1.w) << 16);
  xb[i] = w;
}

// ---------------- pass 1b: dequant qweight -> W^T bf16 [N][K] ----------------
__global__ void dq_w(const int* __restrict__ qw, const int* __restrict__ qz,
                     const float* __restrict__ sc, unsigned short* __restrict__ wt,
                     int N, int K, int group_size) {
  int id = blockIdx.x * blockDim.x + threadIdx.x;  // N*K/64 threads
  int n  = id % N;
  int kb = id / N;                  // 64-k block
  if (kb >= K / 64) return;
  int g = (kb * 64) / group_size;
  unsigned zq = ((unsigned)qz[g * (N >> 3) + (n >> 3)] >> (4 * (n & 7))) & 0xFu;
  float zs = (float)(int)(zq + 1u);
  float s  = sc[(size_t)g * N + n];
  #pragma unroll
  for (int r = 0; r < 8; ++r) {
    unsigned q = (unsigned)qw[(size_t)(kb * 8 + r) * N + n];
    uint4 w;
    #pragma unroll
    for (int h = 0; h < 4; ++h) {
      float v0 = (float)(int)((q >> (8 * h))     & 0xFu) - zs;
      float v1 = (float)(int)((q >> (8 * h + 4)) & 0xFu) - zs;
      ((unsigned*)&w)[h] = f2bf(v0 * s) | (f2bf(v1 * s) << 16);
    }
    *(uint4*)(wt + (size_t)n * K + kb * 64 + r * 8) = w;
  }
}

// ---------------- pass 2: 256^2 8-phase bf16 GEMM ----------------
// LDS: subtile-contiguous [rowgrp(16)][colgrp(2)] x 1024B (16 rows x 32 cols
// bf16), with a per-row chunk rotation: slot lr*4+j holds column-chunk
// (j-(lr>>1))&3. Staging lane s fetches global chunk ((s&3)-(s>>3))&3 of its
// row (pre-permuted source, linear LDS dest — rule #21); frag reads use
// loff = lr*64 + ((lk+(lr>>1))&3)*16. Per quarter-wave each bank-quad is hit
// exactly 2x (minimum for 256B) -> conflict-free b128 reads.
#define BM 256
#define BN 256
#define BK 64

__launch_bounds__(512, 2)
__global__ void gemm_8ph(const unsigned short* __restrict__ A,  // [M][K] bf16
                         const unsigned short* __restrict__ B,  // [N][K] bf16
                         const float* __restrict__ bias,
                         float* __restrict__ out,
                         int M, int N, int K) {
  __shared__ __align__(16) char smem[131072];

  const int nbx = N / BN;
  const int nwg = (M / BM) * nbx;
  const int id  = blockIdx.y * gridDim.x + blockIdx.x;
  const int cpx = nwg >> 3;                       // nwg % 8 == 0 (512)
  const int swzid = (id & 7) * cpx + (id >> 3);   // XCD-contiguous chunks
  const int m0 = (swzid / nbx) * BM;
  const int n0 = (swzid % nbx) * BN;

  const int t    = threadIdx.x;
  const int wid  = t >> 6, lane = t & 63;
  const int wr   = wid >> 2, wc = wid & 3;        // 2(M) x 4(N) waves
  const int lr   = lane & 15, lk = lane >> 4;
  // permuted frag-read offset within a 1024B subtile
  const unsigned loff = (unsigned)(lr * 64 + (((lk + (lr >> 1)) & 3) << 4));

  const int srow = lane >> 2;                          // staging row in subtile
  const int scol = (((lane & 3) - (lane >> 3)) & 3) * 8;  // permuted src chunk

  f4 acc[8][4] = {};

  const int nK = K / BK;

  // Stage one half-tile (128 rows x 64 k): wave w stages row-group w, both
  // col-groups -> 2 gload_lds per wave per phase.
#define STAGE_A(tile, h)                                                          \
  {                                                                               \
    const int _tt = (tile);                                                       \
    _Pragma("unroll")                                                             \
    for (int cg = 0; cg < 2; ++cg) {                                              \
      const unsigned short* _src = A + (size_t)(m0 + (h) * 128 + wid * 16 + srow) * K \
                                     + _tt * BK + cg * 32 + scol;                 \
      char* _dst = smem + (_tt & 1) * 65536 + ((((h) * 8 + wid) * 2 + cg) << 10); \
      gload_lds16(_src, _dst);                                                    \
    }                                                                             \
  }
#define STAGE_B(tile, h)                                                          \
  {                                                                               \
    const int _tt = (tile);                                                       \
    _Pragma("unroll")                                                             \
    for (int cg = 0; cg < 2; ++cg) {                                              \
      const unsigned short* _src = B + (size_t)(n0 + (h) * 128 + wid * 16 + srow) * K \
                                     + _tt * BK + cg * 32 + scol;                 \
      char* _dst = smem + (_tt & 1) * 65536 + 32768 +                             \
                   ((((h) * 8 + wid) * 2 + cg) << 10);                            \
      gload_lds16(_src, _dst);                                                    \
    }                                                                             \
  }

  // Prologue: issue tile0 {B0,B1,A0,A1}, tile1 {B0,B1}; vmcnt(4) completes
  // the oldest 8 = all of tile0.
  STAGE_B(0, 0); STAGE_B(0, 1);
  STAGE_A(0, 0); STAGE_A(0, 1);
  if (nK > 1) {
    STAGE_B(1, 0); STAGE_B(1, 1);
    asm volatile("s_waitcnt vmcnt(4)" ::: "memory");
  } else {
    asm volatile("s_waitcnt vmcnt(0)" ::: "memory");
  }
  __builtin_amdgcn_s_barrier();
  __builtin_amdgcn_sched_barrier(0);

  bf8 a[4][2], b[4][2];

  for (int kt = 0; kt < nK; ++kt) {
    const char* pA = smem + (kt & 1) * 65536;
    const char* pB = pA + 32768;
    const int ra = wr * 8;   // A row-group base (mh=0)
    const int rb = wc * 4;   // B row-group base

    // ---- phase 0: Q(mh0, nf0-1); stage A0 of tile kt+1 ----
    if (kt + 1 < nK) STAGE_A(kt + 1, 0);
    #pragma unroll
    for (int mf = 0; mf < 4; ++mf)
      #pragma unroll
      for (int ks = 0; ks < 2; ++ks)
        a[mf][ks] = *(const bf8*)(pA + (unsigned)((((ra + mf) * 2 + ks) << 10)) + loff);
    #pragma unroll
    for (int nf = 0; nf < 2; ++nf)
      #pragma unroll
      for (int ks = 0; ks < 2; ++ks)
        b[nf][ks] = *(const bf8*)(pB + (unsigned)((((rb + nf) * 2 + ks) << 10)) + loff);
    __builtin_amdgcn_s_barrier();
    __builtin_amdgcn_s_setprio(1);
    #pragma unroll
    for (int mf = 0; mf < 4; ++mf)
      #pragma unroll
      for (int nf = 0; nf < 2; ++nf)
        #pragma unroll
        for (int ks = 0; ks < 2; ++ks)
          acc[mf][nf] = __builtin_amdgcn_mfma_f32_16x16x32_bf16(a[mf][ks], b[nf][ks], acc[mf][nf], 0, 0, 0);
    __builtin_amdgcn_s_setprio(0);
    __builtin_amdgcn_s_barrier();

    // ---- phase 1: Q(mh0, nf2-3); stage A1 of tile kt+1 ----
    if (kt + 1 < nK) STAGE_A(kt + 1, 1);
    #pragma unroll
    for (int nf = 2; nf < 4; ++nf)
      #pragma unroll
      for (int ks = 0; ks < 2; ++ks)
        b[nf][ks] = *(const bf8*)(pB + (unsigned)((((rb + nf) * 2 + ks) << 10)) + loff);
    __builtin_amdgcn_s_barrier();
    __builtin_amdgcn_s_setprio(1);
    #pragma unroll
    for (int mf = 0; mf < 4; ++mf)
      #pragma unroll
      for (int nf = 2; nf < 4; ++nf)
        #pragma unroll
        for (int ks = 0; ks < 2; ++ks)
          acc[mf][nf] = __builtin_amdgcn_mfma_f32_16x16x32_bf16(a[mf][ks], b[nf][ks], acc[mf][nf], 0, 0, 0);
    __builtin_amdgcn_s_setprio(0);
    __builtin_amdgcn_s_barrier();

    // ---- phase 2: Q(mh1, nf2-3); stage B0 of tile kt+2 ----
    if (kt + 2 < nK) STAGE_B(kt + 2, 0);
    #pragma unroll
    for (int mf = 0; mf < 4; ++mf)
      #pragma unroll
      for (int ks = 0; ks < 2; ++ks)
        a[mf][ks] = *(const bf8*)(pA + (unsigned)((((ra + 4 + mf) * 2 + ks) << 10)) + loff);
    __builtin_amdgcn_s_barrier();
    __builtin_amdgcn_s_setprio(1);
    #pragma unroll
    for (int mf = 0; mf < 4; ++mf)
      #pragma unroll
      for (int nf = 2; nf < 4; ++nf)
        #pragma unroll
        for (int ks = 0; ks < 2; ++ks)
          acc[4 + mf][nf] = __builtin_amdgcn_mfma_f32_16x16x32_bf16(a[mf][ks], b[nf][ks], acc[4 + mf][nf], 0, 0, 0);
    __builtin_amdgcn_s_setprio(0);
    __builtin_amdgcn_s_barrier();

    // ---- phase 3: Q(mh1, nf0-1); stage B1 of tile kt+2; counted drain ----
    if (kt + 2 < nK) {
      STAGE_B(kt + 2, 1);
      asm volatile("s_waitcnt vmcnt(4)" ::: "memory");  // tile kt+1 complete
    } else {
      asm volatile("s_waitcnt vmcnt(0)" ::: "memory");  // tail: drain all
    }
    __builtin_amdgcn_s_barrier();
    __builtin_amdgcn_sched_barrier(0);
    __builtin_amdgcn_s_setprio(1);
    #pragma unroll
    for (int mf = 0; mf < 4; ++mf)
      #pragma unroll
      for (int nf = 0; nf < 2; ++nf)
        #pragma unroll
        for (int ks = 0; ks < 2; ++ks)
          acc[4 + mf][nf] = __builtin_amdgcn_mfma_f32_16x16x32_bf16(a[mf][ks], b[nf][ks], acc[4 + mf][nf], 0, 0, 0);
    __builtin_amdgcn_s_setprio(0);
    __builtin_amdgcn_s_barrier();
  }

  // ---- epilogue: C/D layout col=lane&15, row=(lane>>4)*4+reg ----
  #pragma unroll
  for (int ni = 0; ni < 4; ++ni) {
    int col = n0 + wc * 64 + ni * 16 + lr;
    float bv = bias[col];
    #pragma unroll
    for (int mi = 0; mi < 8; ++mi) {
      int row = m0 + wr * 128 + mi * 16 + lk * 4;
      #pragma unroll
      for (int r = 0; r < 4; ++r)
        out[(size_t)(row + r) * N + col] = acc[mi][ni][r] + bv;
    }
  }
#undef STAGE_A
#undef STAGE_B
}

// ---------------- fallback (ws too small): round-1 fused kernel ----------------
#define FBM 128
#define FBN 128
#define FBK 64
__launch_bounds__(256, 2)
__global__ void woq_gemm(const float* __restrict__ x,
                         const int*   __restrict__ qweight,
                         const int*   __restrict__ qzeros,
                         const float* __restrict__ scales,
                         const float* __restrict__ bias,
                         float*       __restrict__ out,
                         int M, int N, int K) {
  __shared__ unsigned short sA[FBM * FBK];
  __shared__ unsigned short sB[FBN * FBK];
  const int t = threadIdx.x;
  const int n0 = blockIdx.x * FBN, m0 = blockIdx.y * FBM;
  const int wid = t >> 6, lane = t & 63;
  const int wr = wid >> 1, wc = wid & 1;
  const int lr = lane & 15, lk = lane >> 4;
  f4 acc[4][4] = {};
  const int c = t & 127, rbase = t >> 7;
  const int segA = t & 7, rowbA = t >> 3;
  const int nK = K / FBK;
  for (int kt = 0; kt < nK; ++kt) {
    const int k0 = kt * FBK;
    __syncthreads();
    #pragma unroll
    for (int p = 0; p < 4; ++p) {
      int row = rowbA + p * 32;
      const float4* src = (const float4*)(x + (size_t)(m0 + row) * K + k0 + segA * 8);
      float4 f0 = src[0], f1 = src[1];
      uint4 w;
      w.x = f2bf(f0.x) | (f2bf(f0.y) << 16);
      w.y = f2bf(f0.z) | (f2bf(f0.w) << 16);
      w.z = f2bf(f1.x) | (f2bf(f1.y) << 16);
      w.w = f2bf(f1.z) | (f2bf(f1.w) << 16);
      unsigned off = (unsigned)(row * (FBK * 2) + segA * 16) ^ ((row & 7) << 4);
      *(uint4*)((char*)sA + off) = w;
    }
    {
      const int g = k0 >> 7;
      const unsigned zq = (unsigned)qzeros[g * (N >> 3) + ((n0 + c) >> 3)];
      const int   zp = (int)((zq >> (4 * ((n0 + c) & 7))) & 0xFu) + 1;
      const float sc = scales[(size_t)g * N + n0 + c];
      #pragma unroll
      for (int p = 0; p < 4; ++p) {
        int r = rbase + p * 2;
        unsigned uq = (unsigned)qweight[(size_t)(kt * 8 + r) * N + n0 + c];
        uint4 w;
        #pragma unroll
        for (int h = 0; h < 4; ++h) {
          int v0 = (int)((uq >> (8 * h))     & 0xFu) - zp;
          int v1 = (int)((uq >> (8 * h + 4)) & 0xFu) - zp;
          ((unsigned*)&w)[h] = f2bf((float)v0 * sc) | (f2bf((float)v1 * sc) << 16);
        }
        unsigned off = (unsigned)(c * (FBK * 2) + r * 16) ^ ((c & 7) << 4);
        *(uint4*)((char*)sB + off) = w;
      }
    }
    __syncthreads();
    #pragma unroll
    for (int ks = 0; ks < 2; ++ks) {
      bf8 a[4], b[4];
      #pragma unroll
      for (int mi = 0; mi < 4; ++mi) {
        int row = wr * 64 + mi * 16 + lr;
        unsigned off = (unsigned)(row * (FBK * 2) + ks * 64 + lk * 16) ^ ((row & 7) << 4);
        a[mi] = *(const bf8*)((const char*)sA + off);
      }
      #pragma unroll
      for (int ni = 0; ni < 4; ++ni) {
        int rowN = wc * 64 + ni * 16 + lr;
        unsigned off = (unsigned)(rowN * (FBK * 2) + ks * 64 + lk * 16) ^ ((rowN & 7) << 4);
        b[ni] = *(const bf8*)((const char*)sB + off);
      }
      #pragma unroll
      for (int mi = 0; mi < 4; ++mi)
        #pragma unroll
        for (int ni = 0; ni < 4; ++ni)
          acc[mi][ni] = __builtin_amdgcn_mfma_f32_16x16x32_bf16(a[mi], b[ni], acc[mi][ni], 0, 0, 0);
    }
  }
  #pragma unroll
  for (int ni = 0; ni < 4; ++ni) {
    int col = n0 + wc * 64 + ni * 16 + lr;
    float bv = bias[col];
    #pragma unroll
    for (int mi = 0; mi < 4; ++mi) {
      int row = m0 + wr * 64 + mi * 16 + lk * 4;
      #pragma unroll
      for (int r = 0; r < 4; ++r)
        out[(size_t)(row + r) * N + col] = acc[mi][ni][r] + bv;
    }
  }
}

extern "C" void kernel_launch(void* const* d_in, const int* in_sizes, int n_in,
                              void* d_out, int out_size, void* d_ws, size_t ws_size,
                              hipStream_t stream) {
  const float* x  = (const float*)d_in[0];
  const int*   qw = (const int*)d_in[1];
  const int*   qz = (const int*)d_in[2];
  const float* sc = (const float*)d_in[3];
  const float* bs = (const float*)d_in[4];
  float* out = (float*)d_out;

  const int N = in_sizes[4];
  const int K = (int)(((long long)in_sizes[1] * 8) / N);
  const int M = (int)((long long)in_sizes[0] / K);
  const int n_groups   = (int)((long long)in_sizes[3] / N);
  const int group_size = K / n_groups;

  const size_t need = ((size_t)M * K + (size_t)N * K) * 2;
  if (ws_size >= need && (M % BM) == 0 && (N % BN) == 0 && (K % BK) == 0 &&
      ((M / BM) * (N / BN)) % 8 == 0) {
    unsigned short* xb = (unsigned short*)d_ws;          // [M][K] bf16
    unsigned short* wt = xb + (size_t)M * K;             // [N][K] bf16

    int n16 = M * K / 8;
    cvt_x<<<(n16 + 255) / 256, 256, 0, stream>>>((const float4*)x, (uint4*)xb, n16);

    int ndq = N * (K / 64);
    dq_w<<<(ndq + 255) / 256, 256, 0, stream>>>(qw, qz, sc, wt, N, K, group_size);

    dim3 grid(N / BN, M / BM);
    gemm_8ph<<<grid, 512, 0, stream>>>(xb, wt, bs, out, M, N, K);
  } else {
    dim3 grid(N / FBN, M / FBM);
    woq_gemm<<<grid, 256, 0, stream>>>(x, qw, qz, sc, bs, out, M, N, K);
  }
}

// Round 5
// 290.459 us; speedup vs baseline: 1.6820x; 1.0385x over previous
//
#include <hip/hip_runtime.h>
#include <hip/hip_bf16.h>
#include <stdint.h>

typedef __bf16 bf8 __attribute__((ext_vector_type(8)));
typedef float  f4  __attribute__((ext_vector_type(4)));

__device__ __forceinline__ unsigned f2bf(float f) {
  union { float f; unsigned u; } v; v.f = f;
  return (v.u + 0x7FFFu + ((v.u >> 16) & 1u)) >> 16;  // RNE f32->bf16
}

// async global->LDS, 16B/lane; LDS dest = wave-uniform base + lane*16
__device__ __forceinline__ void gload_lds16(const void* g, void* l) {
  __builtin_amdgcn_global_load_lds(
      (const __attribute__((address_space(1))) void*)(uintptr_t)g,
      (__attribute__((address_space(3))) void*)(uint32_t)(uintptr_t)l,
      16, 0, 0);
}

// ---------------- pass 1a: x f32 -> bf16 ----------------
__global__ void cvt_x(const float4* __restrict__ x, uint4* __restrict__ xb, int n16) {
  int i = blockIdx.x * blockDim.x + threadIdx.x;
  if (i >= n16) return;
  float4 f0 = x[2 * i], f1 = x[2 * i + 1];
  uint4 w;
  w.x = f2bf(f0.x) | (f2bf(f0.y) << 16);
  w.y = f2bf(f0.z) | (f2bf(f0.w) << 16);
  w.z = f2bf(f1.x) | (f2bf(f1.y) << 16);
  w.w = f2bf(f1.z) | (f2bf(f1.w) << 16);
  xb[i] = w;
}

// ---------------- pass 1b: dequant qweight -> W^T bf16 [N][K] ----------------
__global__ void dq_w(const int* __restrict__ qw, const int* __restrict__ qz,
                     const float* __restrict__ sc, unsigned short* __restrict__ wt,
                     int N, int K, int group_size) {
  int id = blockIdx.x * blockDim.x + threadIdx.x;  // N*K/64 threads
  int n  = id % N;
  int kb = id / N;                  // 64-k block
  if (kb >= K / 64) return;
  int g = (kb * 64) / group_size;
  unsigned zq = ((unsigned)qz[g * (N >> 3) + (n >> 3)] >> (4 * (n & 7))) & 0xFu;
  float zs = (float)(int)(zq + 1u);
  float s  = sc[(size_t)g * N + n];
  #pragma unroll
  for (int r = 0; r < 8; ++r) {
    unsigned q = (unsigned)qw[(size_t)(kb * 8 + r) * N + n];
    uint4 w;
    #pragma unroll
    for (int h = 0; h < 4; ++h) {
      float v0 = (float)(int)((q >> (8 * h))     & 0xFu) - zs;
      float v1 = (float)(int)((q >> (8 * h + 4)) & 0xFu) - zs;
      ((unsigned*)&w)[h] = f2bf(v0 * s) | (f2bf(v1 * s) << 16);
    }
    *(uint4*)(wt + (size_t)n * K + kb * 64 + r * 8) = w;
  }
}

// ---------------- pass 2: 256^2 overlapped-window bf16 GEMM ----------------
// LDS: subtile-contiguous 1024B subtiles (16 rows x 32 cols bf16) with per-row
// chunk rotation (conflict-free b128, verified r4: conflicts=0).
// Schedule: 4 windows per K-tile, ONE barrier each. Window w issues the
// ds_reads for window w+1's fragments, then the 16 MFMAs for window w —
// LDS processing overlaps the MFMA pipe instead of alternating with it.
#define BM 256
#define BN 256
#define BK 64

__launch_bounds__(512, 2)
__global__ void gemm_owin(const unsigned short* __restrict__ A,  // [M][K] bf16
                          const unsigned short* __restrict__ B,  // [N][K] bf16
                          const float* __restrict__ bias,
                          float* __restrict__ out,
                          int M, int N, int K) {
  __shared__ __align__(16) char smem[131072];

  const int nbx = N / BN;
  const int nwg = (M / BM) * nbx;
  const int id  = blockIdx.y * gridDim.x + blockIdx.x;
  const int cpx = nwg >> 3;                       // nwg % 8 == 0
  const int swzid = (id & 7) * cpx + (id >> 3);   // XCD-contiguous chunks
  const int m0 = (swzid / nbx) * BM;
  const int n0 = (swzid % nbx) * BN;

  const int t    = threadIdx.x;
  const int wid  = t >> 6, lane = t & 63;
  const int wr   = wid >> 2, wc = wid & 3;        // 2(M) x 4(N) waves
  const int lr   = lane & 15, lk = lane >> 4;
  // permuted frag-read offset within a 1024B subtile (round-4, conflict-free)
  const unsigned loff = (unsigned)(lr * 64 + (((lk + (lr >> 1)) & 3) << 4));

  const int srow = lane >> 2;                          // staging row in subtile
  const int scol = (((lane & 3) - (lane >> 3)) & 3) * 8;  // permuted src chunk

  f4 acc[8][4] = {};
  bf8 aL[4][2], aH[4][2], b01[2][2], b23[2][2];

  const int nK = K / BK;
  const int ra = wr * 8;   // A row-group base (mh=0)
  const int rb = wc * 4;   // B row-group base

#define STAGE_A(tile, h)                                                          \
  {                                                                               \
    const int _tt = (tile);                                                       \
    _Pragma("unroll")                                                             \
    for (int cg = 0; cg < 2; ++cg) {                                              \
      const unsigned short* _src = A + (size_t)(m0 + (h) * 128 + wid * 16 + srow) * K \
                                     + _tt * BK + cg * 32 + scol;                 \
      char* _dst = smem + (_tt & 1) * 65536 + ((((h) * 8 + wid) * 2 + cg) << 10); \
      gload_lds16(_src, _dst);                                                    \
    }                                                                             \
  }
#define STAGE_B(tile, h)                                                          \
  {                                                                               \
    const int _tt = (tile);                                                       \
    _Pragma("unroll")                                                             \
    for (int cg = 0; cg < 2; ++cg) {                                              \
      const unsigned short* _src = B + (size_t)(n0 + (h) * 128 + wid * 16 + srow) * K \
                                     + _tt * BK + cg * 32 + scol;                 \
      char* _dst = smem + (_tt & 1) * 65536 + 32768 +                             \
                   ((((h) * 8 + wid) * 2 + cg) << 10);                            \
      gload_lds16(_src, _dst);                                                    \
    }                                                                             \
  }
#define RD(p, slot) (*(const bf8*)((p) + ((unsigned)(slot) << 10) + loff))

  // Prologue: stage tile0 fully + tile1 B; complete tile0 (vmcnt(4) = drop 4
  // newest of 12 = keep tile1's B outstanding); preload w0 fragments.
  STAGE_B(0, 0); STAGE_B(0, 1);
  STAGE_A(0, 0); STAGE_A(0, 1);
  if (nK > 1) {
    STAGE_B(1, 0); STAGE_B(1, 1);
    asm volatile("s_waitcnt vmcnt(4)" ::: "memory");
  } else {
    asm volatile("s_waitcnt vmcnt(0)" ::: "memory");
  }
  __builtin_amdgcn_s_barrier();
  __builtin_amdgcn_sched_barrier(0);
  {
    const char* pA = smem;
    const char* pB = smem + 32768;
    #pragma unroll
    for (int mf = 0; mf < 4; ++mf)
      #pragma unroll
      for (int ks = 0; ks < 2; ++ks)
        aL[mf][ks] = RD(pA, (ra + mf) * 2 + ks);
    #pragma unroll
    for (int nf = 0; nf < 2; ++nf)
      #pragma unroll
      for (int ks = 0; ks < 2; ++ks)
        b01[nf][ks] = RD(pB, (rb + nf) * 2 + ks);
  }

  for (int kt = 0; kt < nK; ++kt) {
    const char* pA = smem + (kt & 1) * 65536;
    const char* pB = pA + 32768;

    // ---- w0: reads b23(kt); MFMA Q(mh0 x b01); stage A0(kt+1) ----
    if (kt + 1 < nK) STAGE_A(kt + 1, 0);
    __builtin_amdgcn_s_setprio(1);
    #pragma unroll
    for (int j = 0; j < 2; ++j)
      #pragma unroll
      for (int ks = 0; ks < 2; ++ks)
        b23[j][ks] = RD(pB, (rb + 2 + j) * 2 + ks);
    #pragma unroll
    for (int mf = 0; mf < 4; ++mf)
      #pragma unroll
      for (int nf = 0; nf < 2; ++nf)
        #pragma unroll
        for (int ks = 0; ks < 2; ++ks)
          acc[mf][nf] = __builtin_amdgcn_mfma_f32_16x16x32_bf16(aL[mf][ks], b01[nf][ks], acc[mf][nf], 0, 0, 0);
    __builtin_amdgcn_s_setprio(0);
    __builtin_amdgcn_s_barrier();

    // ---- w1: reads aH(kt); MFMA Q(mh0 x b23); stage A1(kt+1) ----
    if (kt + 1 < nK) STAGE_A(kt + 1, 1);
    __builtin_amdgcn_s_setprio(1);
    #pragma unroll
    for (int mf = 0; mf < 4; ++mf)
      #pragma unroll
      for (int ks = 0; ks < 2; ++ks)
        aH[mf][ks] = RD(pA, (ra + 4 + mf) * 2 + ks);
    #pragma unroll
    for (int mf = 0; mf < 4; ++mf)
      #pragma unroll
      for (int j = 0; j < 2; ++j)
        #pragma unroll
        for (int ks = 0; ks < 2; ++ks)
          acc[mf][2 + j] = __builtin_amdgcn_mfma_f32_16x16x32_bf16(aL[mf][ks], b23[j][ks], acc[mf][2 + j], 0, 0, 0);
    __builtin_amdgcn_s_setprio(0);
    __builtin_amdgcn_s_barrier();

    // ---- w2: MFMA Q(mh1 x b01); stage B0(kt+2) ----
    if (kt + 2 < nK) STAGE_B(kt + 2, 0);
    __builtin_amdgcn_s_setprio(1);
    #pragma unroll
    for (int mf = 0; mf < 4; ++mf)
      #pragma unroll
      for (int nf = 0; nf < 2; ++nf)
        #pragma unroll
        for (int ks = 0; ks < 2; ++ks)
          acc[4 + mf][nf] = __builtin_amdgcn_mfma_f32_16x16x32_bf16(aH[mf][ks], b01[nf][ks], acc[4 + mf][nf], 0, 0, 0);
    __builtin_amdgcn_s_setprio(0);

    // ---- w2/w3 boundary: stage B1(kt+2); counted drain; barrier ----
    if (kt + 2 < nK) {
      STAGE_B(kt + 2, 1);
      asm volatile("s_waitcnt vmcnt(4)" ::: "memory");  // tile kt+1 complete
    } else if (kt + 1 < nK) {
      asm volatile("s_waitcnt vmcnt(0)" ::: "memory");  // tail drain
    }
    __builtin_amdgcn_s_barrier();
    __builtin_amdgcn_sched_barrier(0);

    // ---- w3: reads aL,b01 of tile kt+1; MFMA Q(mh1 x b23) ----
    __builtin_amdgcn_s_setprio(1);
    if (kt + 1 < nK) {
      const char* qA = smem + ((kt + 1) & 1) * 65536;
      const char* qB = qA + 32768;
      #pragma unroll
      for (int mf = 0; mf < 4; ++mf)
        #pragma unroll
        for (int ks = 0; ks < 2; ++ks)
          aL[mf][ks] = RD(qA, (ra + mf) * 2 + ks);
      #pragma unroll
      for (int nf = 0; nf < 2; ++nf)
        #pragma unroll
        for (int ks = 0; ks < 2; ++ks)
          b01[nf][ks] = RD(qB, (rb + nf) * 2 + ks);
    }
    #pragma unroll
    for (int mf = 0; mf < 4; ++mf)
      #pragma unroll
      for (int j = 0; j < 2; ++j)
        #pragma unroll
        for (int ks = 0; ks < 2; ++ks)
          acc[4 + mf][2 + j] = __builtin_amdgcn_mfma_f32_16x16x32_bf16(aH[mf][ks], b23[j][ks], acc[4 + mf][2 + j], 0, 0, 0);
    __builtin_amdgcn_s_setprio(0);
    __builtin_amdgcn_s_barrier();
  }

  // ---- epilogue: C/D layout col=lane&15, row=(lane>>4)*4+reg ----
  #pragma unroll
  for (int ni = 0; ni < 4; ++ni) {
    int col = n0 + wc * 64 + ni * 16 + lr;
    float bv = bias[col];
    #pragma unroll
    for (int mi = 0; mi < 8; ++mi) {
      int row = m0 + wr * 128 + mi * 16 + lk * 4;
      #pragma unroll
      for (int r = 0; r < 4; ++r)
        out[(size_t)(row + r) * N + col] = acc[mi][ni][r] + bv;
    }
  }
#undef STAGE_A
#undef STAGE_B
#undef RD
}

// ---------------- fallback (ws too small): round-1 fused kernel ----------------
#define FBM 128
#define FBN 128
#define FBK 64
__launch_bounds__(256, 2)
__global__ void woq_gemm(const float* __restrict__ x,
                         const int*   __restrict__ qweight,
                         const int*   __restrict__ qzeros,
                         const float* __restrict__ scales,
                         const float* __restrict__ bias,
                         float*       __restrict__ out,
                         int M, int N, int K) {
  __shared__ unsigned short sA[FBM * FBK];
  __shared__ unsigned short sB[FBN * FBK];
  const int t = threadIdx.x;
  const int n0 = blockIdx.x * FBN, m0 = blockIdx.y * FBM;
  const int wid = t >> 6, lane = t & 63;
  const int wr = wid >> 1, wc = wid & 1;
  const int lr = lane & 15, lk = lane >> 4;
  f4 acc[4][4] = {};
  const int c = t & 127, rbase = t >> 7;
  const int segA = t & 7, rowbA = t >> 3;
  const int nK = K / FBK;
  for (int kt = 0; kt < nK; ++kt) {
    const int k0 = kt * FBK;
    __syncthreads();
    #pragma unroll
    for (int p = 0; p < 4; ++p) {
      int row = rowbA + p * 32;
      const float4* src = (const float4*)(x + (size_t)(m0 + row) * K + k0 + segA * 8);
      float4 f0 = src[0], f1 = src[1];
      uint4 w;
      w.x = f2bf(f0.x) | (f2bf(f0.y) << 16);
      w.y = f2bf(f0.z) | (f2bf(f0.w) << 16);
      w.z = f2bf(f1.x) | (f2bf(f1.y) << 16);
      w.w = f2bf(f1.z) | (f2bf(f1.w) << 16);
      unsigned off = (unsigned)(row * (FBK * 2) + segA * 16) ^ ((row & 7) << 4);
      *(uint4*)((char*)sA + off) = w;
    }
    {
      const int g = k0 >> 7;
      const unsigned zq = (unsigned)qzeros[g * (N >> 3) + ((n0 + c) >> 3)];
      const int   zp = (int)((zq >> (4 * ((n0 + c) & 7))) & 0xFu) + 1;
      const float sc = scales[(size_t)g * N + n0 + c];
      #pragma unroll
      for (int p = 0; p < 4; ++p) {
        int r = rbase + p * 2;
        unsigned uq = (unsigned)qweight[(size_t)(kt * 8 + r) * N + n0 + c];
        uint4 w;
        #pragma unroll
        for (int h = 0; h < 4; ++h) {
          int v0 = (int)((uq >> (8 * h))     & 0xFu) - zp;
          int v1 = (int)((uq >> (8 * h + 4)) & 0xFu) - zp;
          ((unsigned*)&w)[h] = f2bf((float)v0 * sc) | (f2bf((float)v1 * sc) << 16);
        }
        unsigned off = (unsigned)(c * (FBK * 2) + r * 16) ^ ((c & 7) << 4);
        *(uint4*)((char*)sB + off) = w;
      }
    }
    __syncthreads();
    #pragma unroll
    for (int ks = 0; ks < 2; ++ks) {
      bf8 a[4], b[4];
      #pragma unroll
      for (int mi = 0; mi < 4; ++mi) {
        int row = wr * 64 + mi * 16 + lr;
        unsigned off = (unsigned)(row * (FBK * 2) + ks * 64 + lk * 16) ^ ((row & 7) << 4);
        a[mi] = *(const bf8*)((const char*)sA + off);
      }
      #pragma unroll
      for (int ni = 0; ni < 4; ++ni) {
        int rowN = wc * 64 + ni * 16 + lr;
        unsigned off = (unsigned)(rowN * (FBK * 2) + ks * 64 + lk * 16) ^ ((rowN & 7) << 4);
        b[ni] = *(const bf8*)((const char*)sB + off);
      }
      #pragma unroll
      for (int mi = 0; mi < 4; ++mi)
        #pragma unroll
        for (int ni = 0; ni < 4; ++ni)
          acc[mi][ni] = __builtin_amdgcn_mfma_f32_16x16x32_bf16(a[mi], b[ni], acc[mi][ni], 0, 0, 0);
    }
  }
  #pragma unroll
  for (int ni = 0; ni < 4; ++ni) {
    int col = n0 + wc * 64 + ni * 16 + lr;
    float bv = bias[col];
    #pragma unroll
    for (int mi = 0; mi < 4; ++mi) {
      int row = m0 + wr * 64 + mi * 16 + lk * 4;
      #pragma unroll
      for (int r = 0; r < 4; ++r)
        out[(size_t)(row + r) * N + col] = acc[mi][ni][r] + bv;
    }
  }
}

extern "C" void kernel_launch(void* const* d_in, const int* in_sizes, int n_in,
                              void* d_out, int out_size, void* d_ws, size_t ws_size,
                              hipStream_t stream) {
  const float* x  = (const float*)d_in[0];
  const int*   qw = (const int*)d_in[1];
  const int*   qz = (const int*)d_in[2];
  const float* sc = (const float*)d_in[3];
  const float* bs = (const float*)d_in[4];
  float* out = (float*)d_out;

  const int N = in_sizes[4];
  const int K = (int)(((long long)in_sizes[1] * 8) / N);
  const int M = (int)((long long)in_sizes[0] / K);
  const int n_groups   = (int)((long long)in_sizes[3] / N);
  const int group_size = K / n_groups;

  const size_t need = ((size_t)M * K + (size_t)N * K) * 2;
  if (ws_size >= need && (M % BM) == 0 && (N % BN) == 0 && (K % BK) == 0 &&
      ((M / BM) * (N / BN)) % 8 == 0) {
    unsigned short* xb = (unsigned short*)d_ws;          // [M][K] bf16
    unsigned short* wt = xb + (size_t)M * K;             // [N][K] bf16

    int n16 = M * K / 8;
    cvt_x<<<(n16 + 255) / 256, 256, 0, stream>>>((const float4*)x, (uint4*)xb, n16);

    int ndq = N * (K / 64);
    dq_w<<<(ndq + 255) / 256, 256, 0, stream>>>(qw, qz, sc, wt, N, K, group_size);

    dim3 grid(N / BN, M / BM);
    gemm_owin<<<grid, 512, 0, stream>>>(xb, wt, bs, out, M, N, K);
  } else {
    dim3 grid(N / FBN, M / FBM);
    woq_gemm<<<grid, 256, 0, stream>>>(x, qw, qz, sc, bs, out, M, N, K);
  }
}

// Round 6
// 288.832 us; speedup vs baseline: 1.6915x; 1.0056x over previous
//
#include <hip/hip_runtime.h>
#include <hip/hip_bf16.h>
#include <stdint.h>

typedef __bf16 bf8 __attribute__((ext_vector_type(8)));
typedef float  f4  __attribute__((ext_vector_type(4)));

__device__ __forceinline__ unsigned f2bf(float f) {
  union { float f; unsigned u; } v; v.f = f;
  return (v.u + 0x7FFFu + ((v.u >> 16) & 1u)) >> 16;  // RNE f32->bf16
}

// async global->LDS, 16B/lane; LDS dest = wave-uniform base + lane*16
__device__ __forceinline__ void gload_lds16(const void* g, void* l) {
  __builtin_amdgcn_global_load_lds(
      (const __attribute__((address_space(1))) void*)(uintptr_t)g,
      (__attribute__((address_space(3))) void*)(uint32_t)(uintptr_t)l,
      16, 0, 0);
}

// ---------------- pass 1a: x f32 -> bf16 ----------------
__global__ void cvt_x(const float4* __restrict__ x, uint4* __restrict__ xb, int n16) {
  int i = blockIdx.x * blockDim.x + threadIdx.x;
  if (i >= n16) return;
  float4 f0 = x[2 * i], f1 = x[2 * i + 1];
  uint4 w;
  w.x = f2bf(f0.x) | (f2bf(f0.y) << 16);
  w.y = f2bf(f0.z) | (f2bf(f0.w) << 16);
  w.z = f2bf(f1.x) | (f2bf(f1.y) << 16);
  w.w = f2bf(f1.z) | (f2bf(f1.w) << 16);
  xb[i] = w;
}

// ---------------- pass 1b: dequant qweight -> W^T bf16 [N][K] ----------------
__global__ void dq_w(const int* __restrict__ qw, const int* __restrict__ qz,
                     const float* __restrict__ sc, unsigned short* __restrict__ wt,
                     int N, int K, int group_size) {
  int id = blockIdx.x * blockDim.x + threadIdx.x;  // N*K/64 threads
  int n  = id % N;
  int kb = id / N;                  // 64-k block
  if (kb >= K / 64) return;
  int g = (kb * 64) / group_size;
  unsigned zq = ((unsigned)qz[g * (N >> 3) + (n >> 3)] >> (4 * (n & 7))) & 0xFu;
  float zs = (float)(int)(zq + 1u);
  float s  = sc[(size_t)g * N + n];
  #pragma unroll
  for (int r = 0; r < 8; ++r) {
    unsigned q = (unsigned)qw[(size_t)(kb * 8 + r) * N + n];
    uint4 w;
    #pragma unroll
    for (int h = 0; h < 4; ++h) {
      float v0 = (float)(int)((q >> (8 * h))     & 0xFu) - zs;
      float v1 = (float)(int)((q >> (8 * h + 4)) & 0xFu) - zs;
      ((unsigned*)&w)[h] = f2bf(v0 * s) | (f2bf(v1 * s) << 16);
    }
    *(uint4*)(wt + (size_t)n * K + kb * 64 + r * 8) = w;
  }
}

// ---------------- pass 2: 256^2 overlapped-window bf16 GEMM ----------------
// LDS: subtile-contiguous 1024B subtiles (16 rows x 32 cols bf16) with per-row
// chunk rotation (conflict-free b128, verified r4: conflicts=0).
// 4 windows/K-tile, ONE barrier each; window w issues ds_reads for window
// w+1's fragments. Round-6: sched_group_barrier templates pin the
// DS_READ || MFMA interleave (compiler was sinking the reads after the MFMA
// cluster -> LDS and MFMA pipes serialized, MfmaUtil stuck at 48%).
#define BM 256
#define BN 256
#define BK 64

#define SGB(mask, n) __builtin_amdgcn_sched_group_barrier((mask), (n), 0)
#define M_MFMA 0x8
#define M_DSRD 0x100

__launch_bounds__(512, 2)
__global__ void gemm_owin(const unsigned short* __restrict__ A,  // [M][K] bf16
                          const unsigned short* __restrict__ B,  // [N][K] bf16
                          const float* __restrict__ bias,
                          float* __restrict__ out,
                          int M, int N, int K) {
  __shared__ __align__(16) char smem[131072];

  const int nbx = N / BN;
  const int nwg = (M / BM) * nbx;
  const int id  = blockIdx.y * gridDim.x + blockIdx.x;
  const int cpx = nwg >> 3;                       // nwg % 8 == 0
  const int swzid = (id & 7) * cpx + (id >> 3);   // XCD-contiguous chunks
  const int m0 = (swzid / nbx) * BM;
  const int n0 = (swzid % nbx) * BN;

  const int t    = threadIdx.x;
  const int wid  = t >> 6, lane = t & 63;
  const int wr   = wid >> 2, wc = wid & 3;        // 2(M) x 4(N) waves
  const int lr   = lane & 15, lk = lane >> 4;
  // permuted frag-read offset within a 1024B subtile (round-4, conflict-free)
  const unsigned loff = (unsigned)(lr * 64 + (((lk + (lr >> 1)) & 3) << 4));

  const int srow = lane >> 2;                          // staging row in subtile
  const int scol = (((lane & 3) - (lane >> 3)) & 3) * 8;  // permuted src chunk

  f4 acc[8][4] = {};
  bf8 aL[4][2], aH[4][2], b01[2][2], b23[2][2];

  const int nK = K / BK;
  const int ra = wr * 8;   // A row-group base (mh=0)
  const int rb = wc * 4;   // B row-group base

#define STAGE_A(tile, h)                                                          \
  {                                                                               \
    const int _tt = (tile);                                                       \
    _Pragma("unroll")                                                             \
    for (int cg = 0; cg < 2; ++cg) {                                              \
      const unsigned short* _src = A + (size_t)(m0 + (h) * 128 + wid * 16 + srow) * K \
                                     + _tt * BK + cg * 32 + scol;                 \
      char* _dst = smem + (_tt & 1) * 65536 + ((((h) * 8 + wid) * 2 + cg) << 10); \
      gload_lds16(_src, _dst);                                                    \
    }                                                                             \
  }
#define STAGE_B(tile, h)                                                          \
  {                                                                               \
    const int _tt = (tile);                                                       \
    _Pragma("unroll")                                                             \
    for (int cg = 0; cg < 2; ++cg) {                                              \
      const unsigned short* _src = B + (size_t)(n0 + (h) * 128 + wid * 16 + srow) * K \
                                     + _tt * BK + cg * 32 + scol;                 \
      char* _dst = smem + (_tt & 1) * 65536 + 32768 +                             \
                   ((((h) * 8 + wid) * 2 + cg) << 10);                            \
      gload_lds16(_src, _dst);                                                    \
    }                                                                             \
  }
#define RD(p, slot) (*(const bf8*)((p) + ((unsigned)(slot) << 10) + loff))

  // Prologue: stage tile0 fully + tile1 B; complete tile0 (vmcnt(4) = keep
  // tile1's B outstanding); preload w0 fragments.
  STAGE_B(0, 0); STAGE_B(0, 1);
  STAGE_A(0, 0); STAGE_A(0, 1);
  if (nK > 1) {
    STAGE_B(1, 0); STAGE_B(1, 1);
    asm volatile("s_waitcnt vmcnt(4)" ::: "memory");
  } else {
    asm volatile("s_waitcnt vmcnt(0)" ::: "memory");
  }
  __builtin_amdgcn_s_barrier();
  __builtin_amdgcn_sched_barrier(0);
  {
    const char* pA = smem;
    const char* pB = smem + 32768;
    #pragma unroll
    for (int mf = 0; mf < 4; ++mf)
      #pragma unroll
      for (int ks = 0; ks < 2; ++ks)
        aL[mf][ks] = RD(pA, (ra + mf) * 2 + ks);
    #pragma unroll
    for (int nf = 0; nf < 2; ++nf)
      #pragma unroll
      for (int ks = 0; ks < 2; ++ks)
        b01[nf][ks] = RD(pB, (rb + nf) * 2 + ks);
  }

  for (int kt = 0; kt < nK; ++kt) {
    const char* pA = smem + (kt & 1) * 65536;
    const char* pB = pA + 32768;

    // ---- w0: reads b23(kt); MFMA Q(mh0 x b01); stage A0(kt+1) ----
    if (kt + 1 < nK) STAGE_A(kt + 1, 0);
    __builtin_amdgcn_s_setprio(1);
    #pragma unroll
    for (int j = 0; j < 2; ++j)
      #pragma unroll
      for (int ks = 0; ks < 2; ++ks)
        b23[j][ks] = RD(pB, (rb + 2 + j) * 2 + ks);
    #pragma unroll
    for (int mf = 0; mf < 4; ++mf)
      #pragma unroll
      for (int nf = 0; nf < 2; ++nf)
        #pragma unroll
        for (int ks = 0; ks < 2; ++ks)
          acc[mf][nf] = __builtin_amdgcn_mfma_f32_16x16x32_bf16(aL[mf][ks], b01[nf][ks], acc[mf][nf], 0, 0, 0);
    // pin interleave: 4 x {1 ds_read, 4 MFMA}
    #pragma unroll
    for (int r = 0; r < 4; ++r) { SGB(M_DSRD, 1); SGB(M_MFMA, 4); }
    __builtin_amdgcn_s_setprio(0);
    __builtin_amdgcn_s_barrier();

    // ---- w1: reads aH(kt); MFMA Q(mh0 x b23); stage A1(kt+1) ----
    if (kt + 1 < nK) STAGE_A(kt + 1, 1);
    __builtin_amdgcn_s_setprio(1);
    #pragma unroll
    for (int mf = 0; mf < 4; ++mf)
      #pragma unroll
      for (int ks = 0; ks < 2; ++ks)
        aH[mf][ks] = RD(pA, (ra + 4 + mf) * 2 + ks);
    #pragma unroll
    for (int mf = 0; mf < 4; ++mf)
      #pragma unroll
      for (int j = 0; j < 2; ++j)
        #pragma unroll
        for (int ks = 0; ks < 2; ++ks)
          acc[mf][2 + j] = __builtin_amdgcn_mfma_f32_16x16x32_bf16(aL[mf][ks], b23[j][ks], acc[mf][2 + j], 0, 0, 0);
    // pin interleave: 4 x {2 ds_read, 4 MFMA}
    #pragma unroll
    for (int r = 0; r < 4; ++r) { SGB(M_DSRD, 2); SGB(M_MFMA, 4); }
    __builtin_amdgcn_s_setprio(0);
    __builtin_amdgcn_s_barrier();

    // ---- w2: MFMA Q(mh1 x b01); stage B0(kt+2) ----
    if (kt + 2 < nK) STAGE_B(kt + 2, 0);
    __builtin_amdgcn_s_setprio(1);
    #pragma unroll
    for (int mf = 0; mf < 4; ++mf)
      #pragma unroll
      for (int nf = 0; nf < 2; ++nf)
        #pragma unroll
        for (int ks = 0; ks < 2; ++ks)
          acc[4 + mf][nf] = __builtin_amdgcn_mfma_f32_16x16x32_bf16(aH[mf][ks], b01[nf][ks], acc[4 + mf][nf], 0, 0, 0);
    __builtin_amdgcn_s_setprio(0);

    // ---- w2/w3 boundary: stage B1(kt+2); counted drain; barrier ----
    if (kt + 2 < nK) {
      STAGE_B(kt + 2, 1);
      asm volatile("s_waitcnt vmcnt(4)" ::: "memory");  // tile kt+1 complete
    } else if (kt + 1 < nK) {
      asm volatile("s_waitcnt vmcnt(0)" ::: "memory");  // tail drain
    }
    __builtin_amdgcn_s_barrier();
    __builtin_amdgcn_sched_barrier(0);

    // ---- w3: reads aL,b01 of tile kt+1 (unconditional, clamped index so
    //      they share a scheduling region with the MFMAs); MFMA Q(mh1xb23) --
    __builtin_amdgcn_s_setprio(1);
    {
      const int nxt = (kt + 1 < nK) ? (kt + 1) : kt;   // clamp: stale-but-safe
      const char* qA = smem + (nxt & 1) * 65536;
      const char* qB = qA + 32768;
      #pragma unroll
      for (int mf = 0; mf < 4; ++mf)
        #pragma unroll
        for (int ks = 0; ks < 2; ++ks)
          aL[mf][ks] = RD(qA, (ra + mf) * 2 + ks);
      #pragma unroll
      for (int nf = 0; nf < 2; ++nf)
        #pragma unroll
        for (int ks = 0; ks < 2; ++ks)
          b01[nf][ks] = RD(qB, (rb + nf) * 2 + ks);
    }
    #pragma unroll
    for (int mf = 0; mf < 4; ++mf)
      #pragma unroll
      for (int j = 0; j < 2; ++j)
        #pragma unroll
        for (int ks = 0; ks < 2; ++ks)
          acc[4 + mf][2 + j] = __builtin_amdgcn_mfma_f32_16x16x32_bf16(aH[mf][ks], b23[j][ks], acc[4 + mf][2 + j], 0, 0, 0);
    // pin interleave: 4 x {3 ds_read, 4 MFMA}
    #pragma unroll
    for (int r = 0; r < 4; ++r) { SGB(M_DSRD, 3); SGB(M_MFMA, 4); }
    __builtin_amdgcn_s_setprio(0);
    __builtin_amdgcn_s_barrier();
  }

  // ---- epilogue: C/D layout col=lane&15, row=(lane>>4)*4+reg ----
  #pragma unroll
  for (int ni = 0; ni < 4; ++ni) {
    int col = n0 + wc * 64 + ni * 16 + lr;
    float bv = bias[col];
    #pragma unroll
    for (int mi = 0; mi < 8; ++mi) {
      int row = m0 + wr * 128 + mi * 16 + lk * 4;
      #pragma unroll
      for (int r = 0; r < 4; ++r)
        out[(size_t)(row + r) * N + col] = acc[mi][ni][r] + bv;
    }
  }
#undef STAGE_A
#undef STAGE_B
#undef RD
}

// ---------------- fallback (ws too small): round-1 fused kernel ----------------
#define FBM 128
#define FBN 128
#define FBK 64
__launch_bounds__(256, 2)
__global__ void woq_gemm(const float* __restrict__ x,
                         const int*   __restrict__ qweight,
                         const int*   __restrict__ qzeros,
                         const float* __restrict__ scales,
                         const float* __restrict__ bias,
                         float*       __restrict__ out,
                         int M, int N, int K) {
  __shared__ unsigned short sA[FBM * FBK];
  __shared__ unsigned short sB[FBN * FBK];
  const int t = threadIdx.x;
  const int n0 = blockIdx.x * FBN, m0 = blockIdx.y * FBM;
  const int wid = t >> 6, lane = t & 63;
  const int wr = wid >> 1, wc = wid & 1;
  const int lr = lane & 15, lk = lane >> 4;
  f4 acc[4][4] = {};
  const int c = t & 127, rbase = t >> 7;
  const int segA = t & 7, rowbA = t >> 3;
  const int nK = K / FBK;
  for (int kt = 0; kt < nK; ++kt) {
    const int k0 = kt * FBK;
    __syncthreads();
    #pragma unroll
    for (int p = 0; p < 4; ++p) {
      int row = rowbA + p * 32;
      const float4* src = (const float4*)(x + (size_t)(m0 + row) * K + k0 + segA * 8);
      float4 f0 = src[0], f1 = src[1];
      uint4 w;
      w.x = f2bf(f0.x) | (f2bf(f0.y) << 16);
      w.y = f2bf(f0.z) | (f2bf(f0.w) << 16);
      w.z = f2bf(f1.x) | (f2bf(f1.y) << 16);
      w.w = f2bf(f1.z) | (f2bf(f1.w) << 16);
      unsigned off = (unsigned)(row * (FBK * 2) + segA * 16) ^ ((row & 7) << 4);
      *(uint4*)((char*)sA + off) = w;
    }
    {
      const int g = k0 >> 7;
      const unsigned zq = (unsigned)qzeros[g * (N >> 3) + ((n0 + c) >> 3)];
      const int   zp = (int)((zq >> (4 * ((n0 + c) & 7))) & 0xFu) + 1;
      const float sc = scales[(size_t)g * N + n0 + c];
      #pragma unroll
      for (int p = 0; p < 4; ++p) {
        int r = rbase + p * 2;
        unsigned uq = (unsigned)qweight[(size_t)(kt * 8 + r) * N + n0 + c];
        uint4 w;
        #pragma unroll
        for (int h = 0; h < 4; ++h) {
          int v0 = (int)((uq >> (8 * h))     & 0xFu) - zp;
          int v1 = (int)((uq >> (8 * h + 4)) & 0xFu) - zp;
          ((unsigned*)&w)[h] = f2bf((float)v0 * sc) | (f2bf((float)v1 * sc) << 16);
        }
        unsigned off = (unsigned)(c * (FBK * 2) + r * 16) ^ ((c & 7) << 4);
        *(uint4*)((char*)sB + off) = w;
      }
    }
    __syncthreads();
    #pragma unroll
    for (int ks = 0; ks < 2; ++ks) {
      bf8 a[4], b[4];
      #pragma unroll
      for (int mi = 0; mi < 4; ++mi) {
        int row = wr * 64 + mi * 16 + lr;
        unsigned off = (unsigned)(row * (FBK * 2) + ks * 64 + lk * 16) ^ ((row & 7) << 4);
        a[mi] = *(const bf8*)((const char*)sA + off);
      }
      #pragma unroll
      for (int ni = 0; ni < 4; ++ni) {
        int rowN = wc * 64 + ni * 16 + lr;
        unsigned off = (unsigned)(rowN * (FBK * 2) + ks * 64 + lk * 16) ^ ((rowN & 7) << 4);
        b[ni] = *(const bf8*)((const char*)sB + off);
      }
      #pragma unroll
      for (int mi = 0; mi < 4; ++mi)
        #pragma unroll
        for (int ni = 0; ni < 4; ++ni)
          acc[mi][ni] = __builtin_amdgcn_mfma_f32_16x16x32_bf16(a[mi], b[ni], acc[mi][ni], 0, 0, 0);
    }
  }
  #pragma unroll
  for (int ni = 0; ni < 4; ++ni) {
    int col = n0 + wc * 64 + ni * 16 + lr;
    float bv = bias[col];
    #pragma unroll
    for (int mi = 0; mi < 4; ++mi) {
      int row = m0 + wr * 64 + mi * 16 + lk * 4;
      #pragma unroll
      for (int r = 0; r < 4; ++r)
        out[(size_t)(row + r) * N + col] = acc[mi][ni][r] + bv;
    }
  }
}

extern "C" void kernel_launch(void* const* d_in, const int* in_sizes, int n_in,
                              void* d_out, int out_size, void* d_ws, size_t ws_size,
                              hipStream_t stream) {
  const float* x  = (const float*)d_in[0];
  const int*   qw = (const int*)d_in[1];
  const int*   qz = (const int*)d_in[2];
  const float* sc = (const float*)d_in[3];
  const float* bs = (const float*)d_in[4];
  float* out = (float*)d_out;

  const int N = in_sizes[4];
  const int K = (int)(((long long)in_sizes[1] * 8) / N);
  const int M = (int)((long long)in_sizes[0] / K);
  const int n_groups   = (int)((long long)in_sizes[3] / N);
  const int group_size = K / n_groups;

  const size_t need = ((size_t)M * K + (size_t)N * K) * 2;
  if (ws_size >= need && (M % BM) == 0 && (N % BN) == 0 && (K % BK) == 0 &&
      ((M / BM) * (N / BN)) % 8 == 0) {
    unsigned short* xb = (unsigned short*)d_ws;          // [M][K] bf16
    unsigned short* wt = xb + (size_t)M * K;             // [N][K] bf16

    int n16 = M * K / 8;
    cvt_x<<<(n16 + 255) / 256, 256, 0, stream>>>((const float4*)x, (uint4*)xb, n16);

    int ndq = N * (K / 64);
    dq_w<<<(ndq + 255) / 256, 256, 0, stream>>>(qw, qz, sc, wt, N, K, group_size);

    dim3 grid(N / BN, M / BM);
    gemm_owin<<<grid, 512, 0, stream>>>(xb, wt, bs, out, M, N, K);
  } else {
    dim3 grid(N / FBN, M / FBM);
    woq_gemm<<<grid, 256, 0, stream>>>(x, qw, qz, sc, bs, out, M, N, K);
  }
}